// Round 1
// baseline (398.682 us; speedup 1.0000x reference)
//
#include <hip/hip_runtime.h>
#include <hip/hip_bf16.h>

#define NS 4096
#define IND 768
#define PP 64
#define DD 256
#define EPSF 1e-8f

// ---------------- init ----------------
__global__ void k_init(unsigned int* __restrict__ minu, float* __restrict__ accum) {
    int t = threadIdx.x;
    if (t < PP) minu[t] = 0x7F800000u;  // +inf bits
    if (t < 4) accum[t] = 0.0f;
}

// ---------------- z = x @ W + b  (fp32 tiled) ----------------
// grid (64, 4), block 256. Tile 64x64, each thread 4x4.
__global__ __launch_bounds__(256) void k_gemm(const float* __restrict__ x,
                                              const float* __restrict__ W,
                                              const float* __restrict__ bias,
                                              float* __restrict__ z) {
    __shared__ float As[16][68];
    __shared__ float Bs[16][68];
    int tid = threadIdx.x;
    int tx = tid & 15, ty = tid >> 4;
    int m0 = blockIdx.x * 64, n0 = blockIdx.y * 64;
    float c[4][4] = {};
    for (int k0 = 0; k0 < IND; k0 += 16) {
        {
            int k = tid & 15;
            int mb = tid >> 4;
#pragma unroll
            for (int r = 0; r < 4; ++r) {
                int m = mb + r * 16;
                As[k][m] = x[(m0 + m) * IND + k0 + k];
            }
            int n = tid & 63;
            int kb = tid >> 6;
#pragma unroll
            for (int r = 0; r < 4; ++r) {
                int k2 = kb + r * 4;
                Bs[k2][n] = W[(k0 + k2) * DD + n0 + n];
            }
        }
        __syncthreads();
#pragma unroll
        for (int k = 0; k < 16; ++k) {
            float a[4], bb[4];
#pragma unroll
            for (int i = 0; i < 4; ++i) a[i] = As[k][ty * 4 + i];
#pragma unroll
            for (int j = 0; j < 4; ++j) bb[j] = Bs[k][tx * 4 + j];
#pragma unroll
            for (int i = 0; i < 4; ++i)
#pragma unroll
                for (int j = 0; j < 4; ++j) c[i][j] += a[i] * bb[j];
        }
        __syncthreads();
    }
#pragma unroll
    for (int i = 0; i < 4; ++i) {
        int m = m0 + ty * 4 + i;
#pragma unroll
        for (int j = 0; j < 4; ++j) {
            int n = n0 + tx * 4 + j;
            z[m * DD + n] = c[i][j] + bias[n];
        }
    }
}

// ---------------- row norms of z ----------------
// block 256 = 4 waves, wave per row; grid 1024
__global__ void k_znorm(const float* __restrict__ z, float* __restrict__ znorm) {
    int wave = threadIdx.x >> 6;
    int lane = threadIdx.x & 63;
    int n = blockIdx.x * 4 + wave;
    const float* row = z + n * DD;
    float s = 0.f;
#pragma unroll
    for (int d = lane; d < DD; d += 64) { float v = row[d]; s += v * v; }
#pragma unroll
    for (int o = 1; o < 64; o <<= 1) s += __shfl_xor(s, o);
    if (lane == 0) znorm[n] = sqrtf(s);
}

// ---------------- prototype norms + pairwise loss ----------------
// grid 64 blocks x 64 threads. block = prototype p, thread = prototype q.
__global__ void k_proto(const float* __restrict__ protos, float* __restrict__ pnorm,
                        float* __restrict__ accum) {
    int p = blockIdx.x;
    int q = threadIdx.x;
    float s = 0.f;
    for (int d = q; d < DD; d += 64) { float v = protos[p * DD + d]; s += v * v; }
    float t = s;
#pragma unroll
    for (int o = 1; o < 64; o <<= 1) t += __shfl_xor(t, o);
    if (q == 0) pnorm[p] = sqrtf(t);

    float s2 = 0.f;
    for (int d = 0; d < DD; ++d) {
        float diff = protos[p * DD + d] - protos[q * DD + d];
        s2 += diff * diff;
    }
    float dd = (q == p) ? 0.f : sqrtf(s2);
#pragma unroll
    for (int o = 1; o < 64; o <<= 1) dd += __shfl_xor(dd, o);
    if (q == 0) atomicAdd(&accum[3], dd);
}

// ---------------- fused cos/dist + all sample reductions ----------------
// grid 256 blocks x 256 threads (4 waves). Wave handles 1 sample/iter, 4 iters.
// lane = prototype index. LDS: prototypes transposed with XOR swizzle (64 KB).
__global__ __launch_bounds__(256) void k_cos(const float* __restrict__ z,
                                             const float* __restrict__ znorm,
                                             const float* __restrict__ protos,
                                             const float* __restrict__ pnorm,
                                             const int* __restrict__ labels,
                                             float* __restrict__ cosout,
                                             unsigned int* __restrict__ minu,
                                             float* __restrict__ accum) {
    __shared__ float protoT[PP * DD];  // protoT[d*64 + (p ^ (d&31))] = proto[p][d]
    int tid = threadIdx.x;
    for (int idx = tid; idx < PP * DD; idx += 256) {
        int p = idx >> 8, d = idx & 255;
        protoT[d * 64 + (p ^ (d & 31))] = protos[idx];
    }
    __syncthreads();

    int wave = tid >> 6, lane = tid & 63;
    int p = lane;
    float pn = pnorm[p];
    float pn2 = pn * pn;
    float regmin = 3.4e38f;
    float s_pz = 0.f, s_cl = 0.f, s_num = 0.f;  // lane 0 only

    for (int it = 0; it < 4; ++it) {
        int n = blockIdx.x * 16 + it * 4 + wave;
        const float4* z4 = (const float4*)(z + n * DD);
        float dot = 0.f;
#pragma unroll 16
        for (int d4 = 0; d4 < 64; ++d4) {
            float4 zv = z4[d4];  // wave-uniform broadcast load
            int d = d4 * 4;
            dot += zv.x * protoT[(d + 0) * 64 + (p ^ ((d + 0) & 31))];
            dot += zv.y * protoT[(d + 1) * 64 + (p ^ ((d + 1) & 31))];
            dot += zv.z * protoT[(d + 2) * 64 + (p ^ ((d + 2) & 31))];
            dot += zv.w * protoT[(d + 3) * 64 + (p ^ ((d + 3) & 31))];
        }
        float zn = znorm[n];
        float cosv = dot / (fmaxf(zn, EPSF) * fmaxf(pn, EPSF));
        float d2 = zn * zn + pn2 - 2.f * dot;
        float dist = sqrtf(fmaxf(d2, 0.f));
        cosout[n * PP + p] = cosv;

        regmin = fminf(regmin, dist);

        unsigned long long bal = __ballot(cosv > 0.5f);
        int cnt = __popcll(bal);

        float mind = dist;
#pragma unroll
        for (int o = 1; o < 64; o <<= 1) mind = fminf(mind, __shfl_xor(mind, o));
        float mx = cosv;
#pragma unroll
        for (int o = 1; o < 32; o <<= 1) mx = fmaxf(mx, __shfl_xor(mx, o));
        float max_pos = __shfl(mx, 0);
        float max_neg = __shfl(mx, 32);

        if (lane == 0) {
            float dcl = (labels[n] == 1) ? (1.f - max_pos) : (1.f - max_neg);
            s_pz += mind;
            s_cl += dcl;
            if (cnt > 16) s_num += 1.f;
        }
    }
    atomicMin(&minu[p], __float_as_uint(regmin));  // dist>=0: bits order-preserving
    if (lane == 0) {
        atomicAdd(&accum[0], s_pz);
        atomicAdd(&accum[1], s_cl);
        atomicAdd(&accum[2], s_num);
    }
}

// ---------------- token_sequences stream write (268 MB) ----------------
// 1 float4 per thread. grid 65536 x 256.
__global__ __launch_bounds__(256) void k_write(const float* __restrict__ cosv,
                                               const float* __restrict__ protos,
                                               float* __restrict__ out) {
    int g = blockIdx.x * 256 + threadIdx.x;
    int d4 = g & 63;
    int row = g >> 6;     // n*64 + p
    int p = row & 63;
    float c = cosv[row];  // wave-uniform (64 consecutive g share one row)
    float4 v = ((const float4*)protos)[p * 64 + d4];
    float4 r;
    r.x = c * v.x; r.y = c * v.y; r.z = c * v.z; r.w = c * v.w;
    ((float4*)out)[g] = r;
}

// ---------------- finalize scalar loss ----------------
__global__ void k_final(const unsigned int* __restrict__ minu,
                        const float* __restrict__ accum,
                        float* __restrict__ out, int out_last) {
    int lane = threadIdx.x;
    float d = __uint_as_float(minu[lane]);
#pragma unroll
    for (int o = 1; o < 64; o <<= 1) d += __shfl_xor(d, o);
    if (lane == 0) {
        float l_zp = d / (float)PP;
        float l_pz = accum[0] / (float)NS;
        float l_cl = accum[1] / (float)NS;
        float l_num = accum[2];
        float l_pp = accum[3] / (float)(PP * (PP - 1));
        out[out_last] = l_zp + l_pz + l_pp + l_num + 2.f * l_cl;
    }
}

extern "C" void kernel_launch(void* const* d_in, const int* in_sizes, int n_in,
                              void* d_out, int out_size, void* d_ws, size_t ws_size,
                              hipStream_t stream) {
    const float* x      = (const float*)d_in[0];
    const int*   labels = (const int*)d_in[1];
    const float* W      = (const float*)d_in[2];
    const float* bias   = (const float*)d_in[3];
    const float* protos = (const float*)d_in[4];
    float* out = (float*)d_out;
    float* ws = (float*)d_ws;

    float* z       = ws;                         // 4096*256
    float* cosbuf  = ws + 1048576;               // 4096*64
    float* znorm   = ws + 1048576 + 262144;      // 4096
    float* pnorm   = znorm + 4096;               // 64
    unsigned int* minu = (unsigned int*)(pnorm + 64);  // 64
    float* accum   = (float*)(minu + 64);        // 4

    k_init<<<1, 64, 0, stream>>>(minu, accum);
    dim3 ggrid(64, 4);
    k_gemm<<<ggrid, 256, 0, stream>>>(x, W, bias, z);
    k_znorm<<<1024, 256, 0, stream>>>(z, znorm);
    k_proto<<<64, 64, 0, stream>>>(protos, pnorm, accum);
    k_cos<<<256, 256, 0, stream>>>(z, znorm, protos, pnorm, labels, cosbuf, minu, accum);
    k_write<<<65536, 256, 0, stream>>>(cosbuf, protos, out);
    k_final<<<1, 64, 0, stream>>>(minu, accum, out, out_size - 1);
}

// Round 2
// 367.967 us; speedup vs baseline: 1.0835x; 1.0835x over previous
//
#include <hip/hip_runtime.h>
#include <hip/hip_bf16.h>

#define NS 4096
#define IND 768
#define PP 64
#define DD 256
#define EPSF 1e-8f
#define KHALF 384

// ---------------- prototype norms + pairwise loss + scalar init ----------------
// grid 64 blocks x 64 threads. block = prototype p, thread = prototype q.
__global__ void k_proto(const float* __restrict__ protos, float* __restrict__ pnorm,
                        float* __restrict__ ppsum, unsigned int* __restrict__ minu,
                        float* __restrict__ accum) {
    int p = blockIdx.x;
    int q = threadIdx.x;
    float s = 0.f;
    for (int d = q; d < DD; d += 64) { float v = protos[p * DD + d]; s += v * v; }
    float t = s;
#pragma unroll
    for (int o = 1; o < 64; o <<= 1) t += __shfl_xor(t, o);
    if (q == 0) pnorm[p] = sqrtf(t);

    float s2 = 0.f;
    for (int d = 0; d < DD; ++d) {
        float diff = protos[p * DD + d] - protos[q * DD + d];
        s2 += diff * diff;
    }
    float dd = (q == p) ? 0.f : sqrtf(s2);
#pragma unroll
    for (int o = 1; o < 64; o <<= 1) dd += __shfl_xor(dd, o);
    if (q == 0) {
        ppsum[p] = dd;                 // no atomics: per-block slot
        minu[p] = 0xFFFFFFFFu;         // uint-max acts as +inf for atomicMin
        if (p == 0) { accum[0] = 0.f; accum[1] = 0.f; accum[2] = 0.f; }
    }
}

// ---------------- z partials: split-K=2, 64x64 tile, 4x4/thread ----------------
// grid (64, 4, 2), block 256. 512 blocks -> 2 blocks/CU, 8 waves/CU.
__global__ __launch_bounds__(256) void k_gemm(const float* __restrict__ x,
                                              const float* __restrict__ W,
                                              float* __restrict__ z0,
                                              float* __restrict__ z1) {
    __shared__ float As[16][68];
    __shared__ float Bs[16][68];
    int tid = threadIdx.x;
    int tx = tid & 15, ty = tid >> 4;
    int m0 = blockIdx.x * 64, n0 = blockIdx.y * 64;
    int kbase = blockIdx.z * KHALF;
    float* __restrict__ zout = blockIdx.z ? z1 : z0;
    float c[4][4] = {};
    for (int k0 = 0; k0 < KHALF; k0 += 16) {
        {
            int k = tid & 15;
            int mb = tid >> 4;
#pragma unroll
            for (int r = 0; r < 4; ++r) {
                int m = mb + r * 16;
                As[k][m] = x[(m0 + m) * IND + kbase + k0 + k];
            }
            int n = tid & 63;
            int kb = tid >> 6;
#pragma unroll
            for (int r = 0; r < 4; ++r) {
                int k2 = kb + r * 4;
                Bs[k2][n] = W[(kbase + k0 + k2) * DD + n0 + n];
            }
        }
        __syncthreads();
#pragma unroll
        for (int k = 0; k < 16; ++k) {
            float a[4], bb[4];
#pragma unroll
            for (int i = 0; i < 4; ++i) a[i] = As[k][ty * 4 + i];
#pragma unroll
            for (int j = 0; j < 4; ++j) bb[j] = Bs[k][tx * 4 + j];
#pragma unroll
            for (int i = 0; i < 4; ++i)
#pragma unroll
                for (int j = 0; j < 4; ++j) c[i][j] += a[i] * bb[j];
        }
        __syncthreads();
    }
#pragma unroll
    for (int i = 0; i < 4; ++i) {
        int m = m0 + ty * 4 + i;
#pragma unroll
        for (int j = 0; j < 4; ++j) zout[m * DD + n0 + tx * 4 + j] = c[i][j];
    }
}

// ---------------- fused: z combine + norms + cos/dist + reductions + token write ----
// grid 256 blocks x 256 threads (4 waves). Each wave owns 4 samples.
// LDS: protoT (xor-swizzled transpose, 64 KB) + rowbuf (16 KB) = 80 KB -> 2 blocks/CU.
__global__ __launch_bounds__(256) void k_cosw(const float* __restrict__ z0,
                                              const float* __restrict__ z1,
                                              const float* __restrict__ bias,
                                              const float* __restrict__ protos,
                                              const float* __restrict__ pnorm,
                                              const int* __restrict__ labels,
                                              float* __restrict__ out,
                                              unsigned int* __restrict__ minu,
                                              float* __restrict__ accum) {
    __shared__ float protoT[PP * DD];                 // [d*64 + (p ^ (d&31))]
    __shared__ __align__(16) float rowbuf[4][4][DD];  // [wave][sample][d]
    int tid = threadIdx.x;
    for (int idx = tid; idx < PP * DD; idx += 256) {
        int p = idx >> 8, d = idx & 255;
        protoT[d * 64 + (p ^ (d & 31))] = protos[idx];
    }

    int w = tid >> 6, lane = tid & 63;
    int p = lane;
    float pn = pnorm[p];
    float pn2 = pn * pn;
    float4 b4 = ((const float4*)bias)[lane];
    int nbase = blockIdx.x * 16 + w * 4;

    float zn[4];
#pragma unroll
    for (int s = 0; s < 4; ++s) {
        int n = nbase + s;
        float4 a = ((const float4*)z0)[n * 64 + lane];
        float4 c = ((const float4*)z1)[n * 64 + lane];
        float4 r;
        r.x = a.x + c.x + b4.x; r.y = a.y + c.y + b4.y;
        r.z = a.z + c.z + b4.z; r.w = a.w + c.w + b4.w;
        float ss = r.x * r.x + r.y * r.y + r.z * r.z + r.w * r.w;
#pragma unroll
        for (int o = 1; o < 64; o <<= 1) ss += __shfl_xor(ss, o);
        zn[s] = sqrtf(ss);
        ((float4*)rowbuf[w][s])[lane] = r;
    }
    __syncthreads();  // protoT staging + rowbuf visibility

    float dot0 = 0.f, dot1 = 0.f, dot2 = 0.f, dot3 = 0.f;
#pragma unroll 8
    for (int d4 = 0; d4 < 64; ++d4) {
        float4 r0 = ((const float4*)rowbuf[w][0])[d4];
        float4 r1 = ((const float4*)rowbuf[w][1])[d4];
        float4 r2 = ((const float4*)rowbuf[w][2])[d4];
        float4 r3 = ((const float4*)rowbuf[w][3])[d4];
        int d = d4 * 4;
        float p0 = protoT[(d + 0) * 64 + (p ^ ((d + 0) & 31))];
        float p1 = protoT[(d + 1) * 64 + (p ^ ((d + 1) & 31))];
        float p2 = protoT[(d + 2) * 64 + (p ^ ((d + 2) & 31))];
        float p3 = protoT[(d + 3) * 64 + (p ^ ((d + 3) & 31))];
        dot0 += r0.x * p0 + r0.y * p1 + r0.z * p2 + r0.w * p3;
        dot1 += r1.x * p0 + r1.y * p1 + r1.z * p2 + r1.w * p3;
        dot2 += r2.x * p0 + r2.y * p1 + r2.z * p2 + r2.w * p3;
        dot3 += r3.x * p0 + r3.y * p1 + r3.z * p2 + r3.w * p3;
    }
    float dots[4] = {dot0, dot1, dot2, dot3};

    float cosv[4];
    float regmin = 3.4e38f;
    float s_pz = 0.f, s_cl = 0.f, s_num = 0.f;
#pragma unroll
    for (int s = 0; s < 4; ++s) {
        int n = nbase + s;
        float dot = dots[s];
        float c = dot / (fmaxf(zn[s], EPSF) * fmaxf(pn, EPSF));
        cosv[s] = c;
        float d2 = zn[s] * zn[s] + pn2 - 2.f * dot;
        float dist = sqrtf(fmaxf(d2, 0.f));
        regmin = fminf(regmin, dist);

        unsigned long long bal = __ballot(c > 0.5f);
        int cnt = __popcll(bal);

        float mind = dist;
#pragma unroll
        for (int o = 1; o < 64; o <<= 1) mind = fminf(mind, __shfl_xor(mind, o));
        float mx = c;
#pragma unroll
        for (int o = 1; o < 32; o <<= 1) mx = fmaxf(mx, __shfl_xor(mx, o));
        float max_pos = __shfl(mx, 0);
        float max_neg = __shfl(mx, 32);
        if (lane == 0) {
            float dcl = (labels[n] == 1) ? (1.f - max_pos) : (1.f - max_neg);
            s_pz += mind;
            s_cl += dcl;
            if (cnt > 16) s_num += 1.f;
        }
    }
    atomicMin(&minu[p], __float_as_uint(regmin));
    if (lane == 0) {
        atomicAdd(&accum[0], s_pz);
        atomicAdd(&accum[1], s_cl);
        atomicAdd(&accum[2], s_num);
    }

    // token write: out[n][pp][d] = cos[n][pp] * protos[pp][d], coalesced 1KB/instr
    const float4* pr4 = (const float4*)protos;
#pragma unroll
    for (int s = 0; s < 4; ++s) {
        int n = nbase + s;
        float4* o4 = (float4*)out + (size_t)n * 4096 + lane;
        float cv = cosv[s];
#pragma unroll 4
        for (int pp = 0; pp < 64; ++pp) {
            float c = __shfl(cv, pp);
            float4 v = pr4[pp * 64 + lane];
            float4 r;
            r.x = c * v.x; r.y = c * v.y; r.z = c * v.z; r.w = c * v.w;
            o4[pp * 64] = r;
        }
    }
}

// ---------------- finalize scalar loss ----------------
__global__ void k_final(const unsigned int* __restrict__ minu,
                        const float* __restrict__ ppsum,
                        const float* __restrict__ accum,
                        float* __restrict__ out, int out_last) {
    int lane = threadIdx.x;
    float v = __uint_as_float(minu[lane]) / (float)PP
            + ppsum[lane] / (float)(PP * (PP - 1));
#pragma unroll
    for (int o = 1; o < 64; o <<= 1) v += __shfl_xor(v, o);
    if (lane == 0) {
        float l_pz = accum[0] / (float)NS;
        float l_cl = accum[1] / (float)NS;
        float l_num = accum[2];
        out[out_last] = v + l_pz + l_num + 2.f * l_cl;
    }
}

extern "C" void kernel_launch(void* const* d_in, const int* in_sizes, int n_in,
                              void* d_out, int out_size, void* d_ws, size_t ws_size,
                              hipStream_t stream) {
    const float* x      = (const float*)d_in[0];
    const int*   labels = (const int*)d_in[1];
    const float* W      = (const float*)d_in[2];
    const float* bias   = (const float*)d_in[3];
    const float* protos = (const float*)d_in[4];
    float* out = (float*)d_out;
    float* ws = (float*)d_ws;

    float* z0    = ws;                    // 4096*256
    float* z1    = ws + 1048576;          // 4096*256
    float* pnorm = ws + 2097152;          // 64
    float* ppsum = pnorm + 64;            // 64
    unsigned int* minu = (unsigned int*)(ppsum + 64);  // 64
    float* accum = (float*)(minu + 64);   // 4

    k_proto<<<64, 64, 0, stream>>>(protos, pnorm, ppsum, minu, accum);
    dim3 ggrid(64, 4, 2);
    k_gemm<<<ggrid, 256, 0, stream>>>(x, W, z0, z1);
    k_cosw<<<256, 256, 0, stream>>>(z0, z1, bias, protos, pnorm, labels, out, minu, accum);
    k_final<<<1, 64, 0, stream>>>(minu, ppsum, accum, out, out_size - 1);
}